// Round 12
// baseline (249.713 us; speedup 1.0000x reference)
//
#include <hip/hip_runtime.h>
#include <hip/hip_fp16.h>

#define NN 50000
#define NPAD 50048
#define NE 800000
#define D 128
#define BPAD 136
#define EGRID 3125   // (NE+255)/256
#define NB 196       // (NN+255)/256
#define GGRID 782    // (NN+63)/64
#define DSLICE 6250  // NN/8

typedef __attribute__((ext_vector_type(8))) short bf16x8;
typedef __attribute__((ext_vector_type(4))) float f32x4;

__device__ inline unsigned short f2bf(float f) {
    unsigned int b = __float_as_uint(f);
    return (unsigned short)((b + 0x7FFFu + ((b >> 16) & 1u)) >> 16);
}
__device__ inline float bf2f(unsigned short u) {
    return __uint_as_float(((unsigned int)u) << 16);
}

// ---------------- CSR build + W conversion (fused role-split) ----------------

__global__ void k_degree_convW(const int* __restrict__ dst, int* __restrict__ cnt,
                               int* __restrict__ rank, int* __restrict__ counter,
                               const float* __restrict__ W0, const float* __restrict__ W1,
                               const float* __restrict__ W2,
                               unsigned short* __restrict__ Wh, unsigned short* __restrict__ Wl) {
    int bid = blockIdx.x;
    int t = threadIdx.x;
    if (bid == 0 && t == 0) counter[0] = 0;   // reset scan ticket
    if (bid < EGRID) {
        int e = bid * 256 + t;
        if (e < NE) {
            int d = dst[e];
            int r = atomicAdd(&cnt[d], 1);
            __builtin_nontemporal_store(r, &rank[e]);
        }
    } else {
        int i = (bid - EGRID) * 256 + t;
        if (i >= 3 * D * D) return;
        int m = i / (D * D), r = i - m * (D * D);
        const float* W = (m == 0) ? W0 : ((m == 1) ? W1 : W2);
        int k = r >> 7, c = r & 127;
        float v = W[r];
        unsigned short h = f2bf(v);
        unsigned short l = f2bf(v - bf2f(h));
        Wh[(size_t)m * D * D + c * D + k] = h;
        Wl[(size_t)m * D * D + c * D + k] = l;
    }
}

// block scan + (last block) top scan, via ticket
__global__ void k_scan_block(const int* __restrict__ cnt, int* __restrict__ excl,
                             int* __restrict__ bsum, int* __restrict__ boff,
                             int* __restrict__ counter) {
    __shared__ int sm[256];
    __shared__ int lastflag;
    int t = threadIdx.x;
    int idx = blockIdx.x * 256 + t;
    int v = (idx < NN) ? cnt[idx] : 0;
    sm[t] = v;
    __syncthreads();
    for (int o = 1; o < 256; o <<= 1) {
        int u = (t >= o) ? sm[t - o] : 0;
        __syncthreads();
        sm[t] += u;
        __syncthreads();
    }
    if (idx < NN) excl[idx] = sm[t] - v;
    if (t == 255) bsum[blockIdx.x] = sm[255];
    __threadfence();
    if (t == 0) {
        int ticket = atomicAdd(counter, 1);
        lastflag = (ticket == NB - 1);
    }
    __syncthreads();
    if (!lastflag) return;
    __threadfence();
    int v2 = (t < NB) ? bsum[t] : 0;
    sm[t] = v2;
    __syncthreads();
    for (int o = 1; o < 256; o <<= 1) {
        int u = (t >= o) ? sm[t - o] : 0;
        __syncthreads();
        sm[t] += u;
        __syncthreads();
    }
    if (t < NB) boff[t] = sm[t] - v2;
}

__global__ void k_scan_add(int* __restrict__ rowptr, const int* __restrict__ boff,
                           const int* __restrict__ cnt, float* __restrict__ dinv) {
    int idx = blockIdx.x * 256 + threadIdx.x;
    if (idx < NN) {
        rowptr[idx] += boff[idx >> 8];
        dinv[idx] = rsqrtf((float)(cnt[idx] + 1));
    } else if (idx == NN) {
        rowptr[NN] = NE;
    }
}

// ---------------- GEMM epilogue ----------------

__device__ inline void gemm_store(f32x4 acc[2][4], const float* __restrict__ dinv,
                                  __half* __restrict__ C, int R0, int C0, int lr, int lg) {
    #pragma unroll
    for (int fr = 0; fr < 2; fr++) {
        int rb = R0 + fr * 16 + lg * 4;
        #pragma unroll
        for (int j = 0; j < 4; j++) {
            int r = rb + j;
            if (r < NN) {
                float s = dinv[r];
                #pragma unroll
                for (int fc = 0; fc < 4; fc++)
                    C[(size_t)r * D + C0 + fc * 16 + lr] =
                        __float2half_rn(acc[fr][fc][j] * s);
            }
        }
    }
}

// ---------------- fused: XCD-sliced CSR fill + layer-0 GEMM ----------------
// GEMM blocks 0..GGRID-1 (LDS-staged Wh). Scatter blocks: 8 per edge chunk;
// block b writes only edges with dst/DSLICE == b&7. Consecutive blockIdx
// round-robins across XCDs, so each col slice (~400KB contiguous) is written
// by one XCD -> no L2 line ping-pong (was 12-17x write amplification).

__global__ __launch_bounds__(256, 2) void k_fill_gemm_x(
        const int* __restrict__ src, const int* __restrict__ dst,
        const int* __restrict__ rowptr, const int* __restrict__ rank,
        int* __restrict__ col,
        const float* __restrict__ X,
        const unsigned short* __restrict__ BhT, const unsigned short* __restrict__ BlT,
        const float* __restrict__ dinv, __half* __restrict__ C) {
    __shared__ short Bs_h[D * BPAD];
    int t = threadIdx.x;
    if (blockIdx.x >= GGRID) {
        int slice = blockIdx.x & 7;
        int chunk = (blockIdx.x - GGRID) >> 3;
        int e = chunk * 256 + t;
        if (e < NE) {
            int d = dst[e];
            if (d / DSLICE == slice) {
                int pos = rowptr[d] + rank[e];
                __builtin_nontemporal_store(src[e], &col[pos]);
            }
        }
        return;
    }
    {
        int c = t >> 1;
        int k0 = (t & 1) * 64;
        const unsigned short* gh = BhT + c * D + k0;
        short* dh = Bs_h + c * BPAD + k0;
        #pragma unroll
        for (int i = 0; i < 8; i++)
            *(int4*)(dh + i * 8) = *(const int4*)(gh + i * 8);
    }
    __syncthreads();

    int w = t >> 6, ln = t & 63;
    int wr = w >> 1, wc = w & 1;
    int R0 = blockIdx.x * 64 + wr * 32;
    int C0 = wc * 64;
    int lr = ln & 15, lg = ln >> 4;

    f32x4 acc[2][4];
    #pragma unroll
    for (int a = 0; a < 2; a++)
        #pragma unroll
        for (int b = 0; b < 4; b++)
            acc[a][b] = (f32x4){0.f, 0.f, 0.f, 0.f};

    const float* Ab = X + (size_t)(R0 + lr) * D + lg * 8;

    #pragma unroll
    for (int ks = 0; ks < 4; ks++) {
        int ko = ks * 32;
        bf16x8 fa_h[2], fa_l[2], fb_h[4], fb_l[4];
        #pragma unroll
        for (int fr = 0; fr < 2; fr++) {
            float4 p0 = *(const float4*)(Ab + fr * 16 * D + ko);
            float4 p1 = *(const float4*)(Ab + fr * 16 * D + ko + 4);
            float vv[8] = {p0.x, p0.y, p0.z, p0.w, p1.x, p1.y, p1.z, p1.w};
            #pragma unroll
            for (int j = 0; j < 8; j++) {
                unsigned short h = f2bf(vv[j]);
                fa_h[fr][j] = (short)h;
                fa_l[fr][j] = (short)f2bf(vv[j] - bf2f(h));
            }
        }
        #pragma unroll
        for (int fc = 0; fc < 4; fc++) {
            int ccol = C0 + fc * 16 + lr;
            fb_h[fc] = *(const bf16x8*)(Bs_h + ccol * BPAD + ko + lg * 8);
            fb_l[fc] = *(const bf16x8*)(BlT + (size_t)ccol * D + ko + lg * 8);
        }
        #pragma unroll
        for (int fr = 0; fr < 2; fr++) {
            #pragma unroll
            for (int fc = 0; fc < 4; fc++) {
                acc[fr][fc] = __builtin_amdgcn_mfma_f32_16x16x32_bf16(
                    fa_h[fr], fb_h[fc], acc[fr][fc], 0, 0, 0);
                acc[fr][fc] = __builtin_amdgcn_mfma_f32_16x16x32_bf16(
                    fa_l[fr], fb_h[fc], acc[fr][fc], 0, 0, 0);
                acc[fr][fc] = __builtin_amdgcn_mfma_f32_16x16x32_bf16(
                    fa_h[fr], fb_l[fc], acc[fr][fc], 0, 0, 0);
            }
        }
    }
    gemm_store(acc, dinv, C, R0, C0, lr, lg);
}

// ---------------- layers 1,2 GEMM: fp16 H, LDS-staged Wh ------------------

__global__ __launch_bounds__(256, 3) void k_gemm_mfma_h(
        const __half* __restrict__ H,
        const unsigned short* __restrict__ BhT, const unsigned short* __restrict__ BlT,
        const float* __restrict__ dinv, __half* __restrict__ C) {
    __shared__ short Bs_h[D * BPAD];
    int t = threadIdx.x;
    {
        int c = t >> 1;
        int k0 = (t & 1) * 64;
        const unsigned short* gh = BhT + c * D + k0;
        short* dh = Bs_h + c * BPAD + k0;
        #pragma unroll
        for (int i = 0; i < 8; i++)
            *(int4*)(dh + i * 8) = *(const int4*)(gh + i * 8);
    }
    __syncthreads();

    int w = t >> 6, ln = t & 63;
    int wr = w >> 1, wc = w & 1;
    int R0 = blockIdx.x * 64 + wr * 32;
    int C0 = wc * 64;
    int lr = ln & 15, lg = ln >> 4;

    f32x4 acc[2][4];
    #pragma unroll
    for (int a = 0; a < 2; a++)
        #pragma unroll
        for (int b = 0; b < 4; b++)
            acc[a][b] = (f32x4){0.f, 0.f, 0.f, 0.f};

    const __half* Ab = H + (size_t)(R0 + lr) * D + lg * 8;

    #pragma unroll
    for (int ks = 0; ks < 4; ks++) {
        int ko = ks * 32;
        bf16x8 fa_h[2], fa_l[2], fb_h[4], fb_l[4];
        #pragma unroll
        for (int fr = 0; fr < 2; fr++) {
            float4 p = *(const float4*)(Ab + fr * 16 * D + ko);
            const __half2* hp = (const __half2*)&p;
            #pragma unroll
            for (int q = 0; q < 4; q++) {
                float2 fv = __half22float2(hp[q]);
                unsigned short h0 = f2bf(fv.x), h1 = f2bf(fv.y);
                fa_h[fr][q * 2]     = (short)h0;
                fa_h[fr][q * 2 + 1] = (short)h1;
                fa_l[fr][q * 2]     = (short)f2bf(fv.x - bf2f(h0));
                fa_l[fr][q * 2 + 1] = (short)f2bf(fv.y - bf2f(h1));
            }
        }
        #pragma unroll
        for (int fc = 0; fc < 4; fc++) {
            int ccol = C0 + fc * 16 + lr;
            fb_h[fc] = *(const bf16x8*)(Bs_h + ccol * BPAD + ko + lg * 8);
            fb_l[fc] = *(const bf16x8*)(BlT + (size_t)ccol * D + ko + lg * 8);
        }
        #pragma unroll
        for (int fr = 0; fr < 2; fr++) {
            #pragma unroll
            for (int fc = 0; fc < 4; fc++) {
                acc[fr][fc] = __builtin_amdgcn_mfma_f32_16x16x32_bf16(
                    fa_h[fr], fb_h[fc], acc[fr][fc], 0, 0, 0);
                acc[fr][fc] = __builtin_amdgcn_mfma_f32_16x16x32_bf16(
                    fa_l[fr], fb_h[fc], acc[fr][fc], 0, 0, 0);
                acc[fr][fc] = __builtin_amdgcn_mfma_f32_16x16x32_bf16(
                    fa_h[fr], fb_l[fc], acc[fr][fc], 0, 0, 0);
            }
        }
    }
    gemm_store(acc, dinv, C, R0, C0, lr, lg);
}

// ---------------- Aggregation: 16 lanes/node, 16 gathers in flight --------

__device__ inline void agg_accum(const float4& rv, float a[8]) {
    const __half2* hp = (const __half2*)&rv;
    #pragma unroll
    for (int q = 0; q < 4; q++) {
        float2 fv = __half22float2(hp[q]);
        a[q * 2] += fv.x;
        a[q * 2 + 1] += fv.y;
    }
}

__device__ inline void agg_core(const __half* __restrict__ T,
                                const int* __restrict__ rowptr,
                                const int* __restrict__ col,
                                int i, int f, int lane, float a[8]) {
    int gb = lane & 48;
    int sl16 = lane & 15;
    {
        float4 raw = *(const float4*)(T + (size_t)i * D + f);
        const __half2* hp = (const __half2*)&raw;
        #pragma unroll
        for (int q = 0; q < 4; q++) {
            float2 fv = __half22float2(hp[q]);
            a[q * 2] = fv.x;
            a[q * 2 + 1] = fv.y;
        }
    }
    int r0 = rowptr[i], r1 = rowptr[i + 1];
    for (int e = r0; e < r1; e += 16) {
        int idx = e + sl16;
        if (idx > r1 - 1) idx = r1 - 1;
        int cv = col[idx];
        int m = r1 - e;
        m = m > 16 ? 16 : m;
        int ss[16];
        #pragma unroll
        for (int u = 0; u < 16; u++) ss[u] = __shfl(cv, gb + u, 64);
        float4 rv[16];
        #pragma unroll
        for (int u = 0; u < 16; u++)
            rv[u] = *(const float4*)(T + (size_t)ss[u] * D + f);
        #pragma unroll
        for (int u = 0; u < 16; u++)
            if (u < m) agg_accum(rv[u], a);
    }
}

__global__ __launch_bounds__(256) void k_agg_relu(const __half* __restrict__ T,
                                                  const int* __restrict__ rowptr,
                                                  const int* __restrict__ col,
                                                  const float* __restrict__ dinv,
                                                  const float* __restrict__ bias,
                                                  __half* __restrict__ Hout) {
    int i = blockIdx.x * 16 + (threadIdx.x >> 4);
    int lane = threadIdx.x & 63;
    int sl = threadIdx.x & 15;
    int f = sl * 8;
    float di = dinv[i];
    float a[8];
    agg_core(T, rowptr, col, i, f, lane, a);
    float4 bv0 = *(const float4*)(bias + f);
    float4 bv1 = *(const float4*)(bias + f + 4);
    float bb[8] = {bv0.x, bv0.y, bv0.z, bv0.w, bv1.x, bv1.y, bv1.z, bv1.w};
    __half2 o[4];
    #pragma unroll
    for (int q = 0; q < 4; q++) {
        float x0 = fmaxf(a[q * 2] * di + bb[q * 2], 0.f);
        float x1 = fmaxf(a[q * 2 + 1] * di + bb[q * 2 + 1], 0.f);
        o[q] = __floats2half2_rn(x0, x1);
    }
    *(float4*)(Hout + (size_t)i * D + f) = *(float4*)o;
}

__global__ __launch_bounds__(256) void k_agg_out(const __half* __restrict__ T,
                                                 const int* __restrict__ rowptr,
                                                 const int* __restrict__ col,
                                                 const float* __restrict__ dinv,
                                                 const float* __restrict__ bias,
                                                 float* __restrict__ Of) {
    int i = blockIdx.x * 16 + (threadIdx.x >> 4);
    int lane = threadIdx.x & 63;
    int sl = threadIdx.x & 15;
    int f = sl * 8;
    float di = dinv[i];
    float a[8];
    agg_core(T, rowptr, col, i, f, lane, a);
    float4 bv0 = *(const float4*)(bias + f);
    float4 bv1 = *(const float4*)(bias + f + 4);
    float4 o0 = make_float4(a[0] * di + bv0.x, a[1] * di + bv0.y,
                            a[2] * di + bv0.z, a[3] * di + bv0.w);
    float4 o1 = make_float4(a[4] * di + bv1.x, a[5] * di + bv1.y,
                            a[6] * di + bv1.z, a[7] * di + bv1.w);
    *(float4*)(Of + (size_t)i * D + f) = o0;
    *(float4*)(Of + (size_t)i * D + f + 4) = o1;
}

// ---------------- launch ----------------

extern "C" void kernel_launch(void* const* d_in, const int* in_sizes, int n_in,
                              void* d_out, int out_size, void* d_ws, size_t ws_size,
                              hipStream_t stream) {
    const float* x  = (const float*)d_in[0];
    const int* edge = (const int*)d_in[1];
    const float* W0 = (const float*)d_in[2];
    const float* b0 = (const float*)d_in[3];
    const float* W1 = (const float*)d_in[4];
    const float* b1 = (const float*)d_in[5];
    const float* W2 = (const float*)d_in[6];
    const float* b2 = (const float*)d_in[7];
    const int* src = edge;
    const int* dst = edge + NE;
    float* out = (float*)d_out;

    char* ws = (char*)d_ws;
    size_t off = 0;
    auto alloc = [&](size_t bytes) {
        void* p = ws + off;
        off += (bytes + 255) & ~(size_t)255;
        return p;
    };
    int*   cnt     = (int*)alloc(NN * 4);
    int*   counter = (int*)alloc(256);
    int*   rowptr  = (int*)alloc((NN + 1) * 4);
    float* dinv    = (float*)alloc(NN * 4);
    int*   bsum    = (int*)alloc(256 * 4);
    int*   boff    = (int*)alloc(256 * 4);
    int*   rank    = (int*)alloc((size_t)NE * 4);
    int*   col     = (int*)alloc((size_t)NE * 4);
    unsigned short* Wh = (unsigned short*)alloc(3 * D * D * 2);
    unsigned short* Wl = (unsigned short*)alloc(3 * D * D * 2);
    __half* Ta = (__half*)alloc((size_t)NPAD * D * 2);
    __half* Tb = (__half*)alloc((size_t)NPAD * D * 2);
    __half* Hb = (__half*)alloc((size_t)NPAD * D * 2);

    hipMemsetAsync(cnt, 0, NN * 4, stream);

    k_degree_convW<<<EGRID + 192, 256, 0, stream>>>(dst, cnt, rank, counter,
                                                    W0, W1, W2, Wh, Wl);
    k_scan_block<<<NB, 256, 0, stream>>>(cnt, rowptr, bsum, boff, counter);
    k_scan_add<<<(NN + 256) / 256, 256, 0, stream>>>(rowptr, boff, cnt, dinv);

    const int agrid = NN / 16;          // 3125

    // fused: XCD-sliced CSR fill + layer-0 GEMM (Ta = dinv * (x @ W0))
    k_fill_gemm_x<<<GGRID + 8 * EGRID, 256, 0, stream>>>(src, dst, rowptr, rank, col,
                                                         x, Wh, Wl, dinv, Ta);
    // h1 = relu(agg(Ta)+b0)  [fp16]
    k_agg_relu<<<agrid, 256, 0, stream>>>(Ta, rowptr, col, dinv, b0, Hb);
    // Tb = dinv * (h1 @ W1)
    k_gemm_mfma_h<<<GGRID, 256, 0, stream>>>(Hb, Wh + D * D, Wl + D * D, dinv, Tb);
    // h2 = relu(agg(Tb)+b1)  [fp16]
    k_agg_relu<<<agrid, 256, 0, stream>>>(Tb, rowptr, col, dinv, b1, Hb);
    // Ta = dinv * (h2 @ W2)
    k_gemm_mfma_h<<<GGRID, 256, 0, stream>>>(Hb, Wh + 2 * D * D, Wl + 2 * D * D, dinv, Ta);
    // out = dinv*agg(Ta) + b2  [fp32]
    k_agg_out<<<agrid, 256, 0, stream>>>(Ta, rowptr, col, dinv, b2, out);
}

// Round 13
// 230.789 us; speedup vs baseline: 1.0820x; 1.0820x over previous
//
#include <hip/hip_runtime.h>
#include <hip/hip_fp16.h>

#define NN 50000
#define NPAD 50048
#define NE 800000
#define D 128
#define BPAD 136
#define EGRID 3125   // (NE+255)/256
#define NB 196       // (NN+255)/256
#define GGRID 782    // (NN+63)/64

typedef __attribute__((ext_vector_type(8))) short bf16x8;
typedef __attribute__((ext_vector_type(4))) float f32x4;

__device__ inline unsigned short f2bf(float f) {
    unsigned int b = __float_as_uint(f);
    return (unsigned short)((b + 0x7FFFu + ((b >> 16) & 1u)) >> 16);
}
__device__ inline float bf2f(unsigned short u) {
    return __uint_as_float(((unsigned int)u) << 16);
}

// ---------------- CSR build + W conversion (fused role-split) ----------------

__global__ void k_degree_convW(const int* __restrict__ dst, int* __restrict__ cnt,
                               int* __restrict__ rank, int* __restrict__ counter,
                               const float* __restrict__ W0, const float* __restrict__ W1,
                               const float* __restrict__ W2,
                               unsigned short* __restrict__ Wh, unsigned short* __restrict__ Wl) {
    int bid = blockIdx.x;
    int t = threadIdx.x;
    if (bid == 0 && t == 0) counter[0] = 0;   // reset scan ticket
    if (bid < EGRID) {
        int e = bid * 256 + t;
        if (e < NE) {
            int d = dst[e];
            int r = atomicAdd(&cnt[d], 1);
            __builtin_nontemporal_store(r, &rank[e]);
        }
    } else {
        int i = (bid - EGRID) * 256 + t;
        if (i >= 3 * D * D) return;
        int m = i / (D * D), r = i - m * (D * D);
        const float* W = (m == 0) ? W0 : ((m == 1) ? W1 : W2);
        int k = r >> 7, c = r & 127;
        float v = W[r];
        unsigned short h = f2bf(v);
        unsigned short l = f2bf(v - bf2f(h));
        Wh[(size_t)m * D * D + c * D + k] = h;
        Wl[(size_t)m * D * D + c * D + k] = l;
    }
}

// block scan + (last block) top scan, via ticket. excl = block-local
// exclusive scan of cnt; boff = per-block base. Final rowptr[i] =
// excl[i] + boff[i>>8], computed inline by consumers (no scan_add pass).
__global__ void k_scan_block(const int* __restrict__ cnt, int* __restrict__ excl,
                             int* __restrict__ bsum, int* __restrict__ boff,
                             int* __restrict__ counter) {
    __shared__ int sm[256];
    __shared__ int lastflag;
    int t = threadIdx.x;
    int idx = blockIdx.x * 256 + t;
    int v = (idx < NN) ? cnt[idx] : 0;
    sm[t] = v;
    __syncthreads();
    for (int o = 1; o < 256; o <<= 1) {
        int u = (t >= o) ? sm[t - o] : 0;
        __syncthreads();
        sm[t] += u;
        __syncthreads();
    }
    if (idx < NN) excl[idx] = sm[t] - v;
    if (t == 255) bsum[blockIdx.x] = sm[255];
    __threadfence();
    if (t == 0) {
        int ticket = atomicAdd(counter, 1);
        lastflag = (ticket == NB - 1);
    }
    __syncthreads();
    if (!lastflag) return;
    __threadfence();
    int v2 = (t < NB) ? bsum[t] : 0;
    sm[t] = v2;
    __syncthreads();
    for (int o = 1; o < 256; o <<= 1) {
        int u = (t >= o) ? sm[t - o] : 0;
        __syncthreads();
        sm[t] += u;
        __syncthreads();
    }
    if (t < NB) boff[t] = sm[t] - v2;
}

// ---------------- GEMM epilogue (dinv computed from cnt) ----------------

__device__ inline void gemm_store(f32x4 acc[2][4], const int* __restrict__ cnt,
                                  __half* __restrict__ C, int R0, int C0, int lr, int lg) {
    #pragma unroll
    for (int fr = 0; fr < 2; fr++) {
        int rb = R0 + fr * 16 + lg * 4;
        #pragma unroll
        for (int j = 0; j < 4; j++) {
            int r = rb + j;
            if (r < NN) {
                float s = rsqrtf((float)(cnt[r] + 1));
                #pragma unroll
                for (int fc = 0; fc < 4; fc++)
                    C[(size_t)r * D + C0 + fc * 16 + lr] =
                        __float2half_rn(acc[fr][fc][j] * s);
            }
        }
    }
}

// ---------------- fused: CSR fill (scatter) + layer-0 GEMM (role-split) ----
// GEMM blocks 0..GGRID-1: Ta = dinv * (x @ W0), Wh LDS-staged.
// Blocks GGRID..: atomic-free scatter, rowptr computed inline.

__global__ __launch_bounds__(256, 2) void k_fill_gemm_x(
        const int* __restrict__ src, const int* __restrict__ dst,
        const int* __restrict__ excl, const int* __restrict__ boff,
        const int* __restrict__ rank, int* __restrict__ col,
        const float* __restrict__ X,
        const unsigned short* __restrict__ BhT, const unsigned short* __restrict__ BlT,
        const int* __restrict__ cnt, __half* __restrict__ C) {
    __shared__ short Bs_h[D * BPAD];
    int t = threadIdx.x;
    if (blockIdx.x >= GGRID) {
        int e = (blockIdx.x - GGRID) * 256 + t;
        if (e < NE) {
            int d = dst[e];
            int pos = excl[d] + boff[d >> 8] + rank[e];
            __builtin_nontemporal_store(src[e], &col[pos]);
        }
        return;
    }
    {
        int c = t >> 1;
        int k0 = (t & 1) * 64;
        const unsigned short* gh = BhT + c * D + k0;
        short* dh = Bs_h + c * BPAD + k0;
        #pragma unroll
        for (int i = 0; i < 8; i++)
            *(int4*)(dh + i * 8) = *(const int4*)(gh + i * 8);
    }
    __syncthreads();

    int w = t >> 6, ln = t & 63;
    int wr = w >> 1, wc = w & 1;
    int R0 = blockIdx.x * 64 + wr * 32;
    int C0 = wc * 64;
    int lr = ln & 15, lg = ln >> 4;

    f32x4 acc[2][4];
    #pragma unroll
    for (int a = 0; a < 2; a++)
        #pragma unroll
        for (int b = 0; b < 4; b++)
            acc[a][b] = (f32x4){0.f, 0.f, 0.f, 0.f};

    const float* Ab = X + (size_t)(R0 + lr) * D + lg * 8;

    #pragma unroll
    for (int ks = 0; ks < 4; ks++) {
        int ko = ks * 32;
        bf16x8 fa_h[2], fa_l[2], fb_h[4], fb_l[4];
        #pragma unroll
        for (int fr = 0; fr < 2; fr++) {
            float4 p0 = *(const float4*)(Ab + fr * 16 * D + ko);
            float4 p1 = *(const float4*)(Ab + fr * 16 * D + ko + 4);
            float vv[8] = {p0.x, p0.y, p0.z, p0.w, p1.x, p1.y, p1.z, p1.w};
            #pragma unroll
            for (int j = 0; j < 8; j++) {
                unsigned short h = f2bf(vv[j]);
                fa_h[fr][j] = (short)h;
                fa_l[fr][j] = (short)f2bf(vv[j] - bf2f(h));
            }
        }
        #pragma unroll
        for (int fc = 0; fc < 4; fc++) {
            int ccol = C0 + fc * 16 + lr;
            fb_h[fc] = *(const bf16x8*)(Bs_h + ccol * BPAD + ko + lg * 8);
            fb_l[fc] = *(const bf16x8*)(BlT + (size_t)ccol * D + ko + lg * 8);
        }
        #pragma unroll
        for (int fr = 0; fr < 2; fr++) {
            #pragma unroll
            for (int fc = 0; fc < 4; fc++) {
                acc[fr][fc] = __builtin_amdgcn_mfma_f32_16x16x32_bf16(
                    fa_h[fr], fb_h[fc], acc[fr][fc], 0, 0, 0);
                acc[fr][fc] = __builtin_amdgcn_mfma_f32_16x16x32_bf16(
                    fa_l[fr], fb_h[fc], acc[fr][fc], 0, 0, 0);
                acc[fr][fc] = __builtin_amdgcn_mfma_f32_16x16x32_bf16(
                    fa_h[fr], fb_l[fc], acc[fr][fc], 0, 0, 0);
            }
        }
    }
    gemm_store(acc, cnt, C, R0, C0, lr, lg);
}

// ---------------- layers 1,2 GEMM: fp16 H, LDS-staged Wh ------------------

__global__ __launch_bounds__(256, 4) void k_gemm_mfma_h(
        const __half* __restrict__ H,
        const unsigned short* __restrict__ BhT, const unsigned short* __restrict__ BlT,
        const int* __restrict__ cnt, __half* __restrict__ C) {
    __shared__ short Bs_h[D * BPAD];
    int t = threadIdx.x;
    {
        int c = t >> 1;
        int k0 = (t & 1) * 64;
        const unsigned short* gh = BhT + c * D + k0;
        short* dh = Bs_h + c * BPAD + k0;
        #pragma unroll
        for (int i = 0; i < 8; i++)
            *(int4*)(dh + i * 8) = *(const int4*)(gh + i * 8);
    }
    __syncthreads();

    int w = t >> 6, ln = t & 63;
    int wr = w >> 1, wc = w & 1;
    int R0 = blockIdx.x * 64 + wr * 32;
    int C0 = wc * 64;
    int lr = ln & 15, lg = ln >> 4;

    f32x4 acc[2][4];
    #pragma unroll
    for (int a = 0; a < 2; a++)
        #pragma unroll
        for (int b = 0; b < 4; b++)
            acc[a][b] = (f32x4){0.f, 0.f, 0.f, 0.f};

    const __half* Ab = H + (size_t)(R0 + lr) * D + lg * 8;

    #pragma unroll
    for (int ks = 0; ks < 4; ks++) {
        int ko = ks * 32;
        bf16x8 fa_h[2], fa_l[2], fb_h[4], fb_l[4];
        #pragma unroll
        for (int fr = 0; fr < 2; fr++) {
            float4 p = *(const float4*)(Ab + fr * 16 * D + ko);
            const __half2* hp = (const __half2*)&p;
            #pragma unroll
            for (int q = 0; q < 4; q++) {
                float2 fv = __half22float2(hp[q]);
                unsigned short h0 = f2bf(fv.x), h1 = f2bf(fv.y);
                fa_h[fr][q * 2]     = (short)h0;
                fa_h[fr][q * 2 + 1] = (short)h1;
                fa_l[fr][q * 2]     = (short)f2bf(fv.x - bf2f(h0));
                fa_l[fr][q * 2 + 1] = (short)f2bf(fv.y - bf2f(h1));
            }
        }
        #pragma unroll
        for (int fc = 0; fc < 4; fc++) {
            int ccol = C0 + fc * 16 + lr;
            fb_h[fc] = *(const bf16x8*)(Bs_h + ccol * BPAD + ko + lg * 8);
            fb_l[fc] = *(const bf16x8*)(BlT + (size_t)ccol * D + ko + lg * 8);
        }
        #pragma unroll
        for (int fr = 0; fr < 2; fr++) {
            #pragma unroll
            for (int fc = 0; fc < 4; fc++) {
                acc[fr][fc] = __builtin_amdgcn_mfma_f32_16x16x32_bf16(
                    fa_h[fr], fb_h[fc], acc[fr][fc], 0, 0, 0);
                acc[fr][fc] = __builtin_amdgcn_mfma_f32_16x16x32_bf16(
                    fa_l[fr], fb_h[fc], acc[fr][fc], 0, 0, 0);
                acc[fr][fc] = __builtin_amdgcn_mfma_f32_16x16x32_bf16(
                    fa_h[fr], fb_l[fc], acc[fr][fc], 0, 0, 0);
            }
        }
    }
    gemm_store(acc, cnt, C, R0, C0, lr, lg);
}

// ---------------- Aggregation: 16 lanes/node, 16 gathers in flight --------
// rowptr computed inline: r = excl[i] + boff[i>>8]; i+1==NN -> NE.

__device__ inline void agg_accum(const float4& rv, float a[8]) {
    const __half2* hp = (const __half2*)&rv;
    #pragma unroll
    for (int q = 0; q < 4; q++) {
        float2 fv = __half22float2(hp[q]);
        a[q * 2] += fv.x;
        a[q * 2 + 1] += fv.y;
    }
}

__device__ inline void agg_core(const __half* __restrict__ T,
                                const int* __restrict__ excl,
                                const int* __restrict__ boff,
                                const int* __restrict__ col,
                                int i, int f, int lane, float a[8]) {
    int gb = lane & 48;
    int sl16 = lane & 15;
    {
        float4 raw = *(const float4*)(T + (size_t)i * D + f);
        const __half2* hp = (const __half2*)&raw;
        #pragma unroll
        for (int q = 0; q < 4; q++) {
            float2 fv = __half22float2(hp[q]);
            a[q * 2] = fv.x;
            a[q * 2 + 1] = fv.y;
        }
    }
    int r0 = excl[i] + boff[i >> 8];
    int r1 = (i == NN - 1) ? NE : (excl[i + 1] + boff[(i + 1) >> 8]);
    for (int e = r0; e < r1; e += 16) {
        int idx = e + sl16;
        if (idx > r1 - 1) idx = r1 - 1;
        int cv = col[idx];
        int m = r1 - e;
        m = m > 16 ? 16 : m;
        int ss[16];
        #pragma unroll
        for (int u = 0; u < 16; u++) ss[u] = __shfl(cv, gb + u, 64);
        float4 rv[16];
        #pragma unroll
        for (int u = 0; u < 16; u++)
            rv[u] = *(const float4*)(T + (size_t)ss[u] * D + f);
        #pragma unroll
        for (int u = 0; u < 16; u++)
            if (u < m) agg_accum(rv[u], a);
    }
}

__global__ __launch_bounds__(256) void k_agg_relu(const __half* __restrict__ T,
                                                  const int* __restrict__ excl,
                                                  const int* __restrict__ boff,
                                                  const int* __restrict__ col,
                                                  const int* __restrict__ cnt,
                                                  const float* __restrict__ bias,
                                                  __half* __restrict__ Hout) {
    int i = blockIdx.x * 16 + (threadIdx.x >> 4);
    int lane = threadIdx.x & 63;
    int sl = threadIdx.x & 15;
    int f = sl * 8;
    float di = rsqrtf((float)(cnt[i] + 1));
    float a[8];
    agg_core(T, excl, boff, col, i, f, lane, a);
    float4 bv0 = *(const float4*)(bias + f);
    float4 bv1 = *(const float4*)(bias + f + 4);
    float bb[8] = {bv0.x, bv0.y, bv0.z, bv0.w, bv1.x, bv1.y, bv1.z, bv1.w};
    __half2 o[4];
    #pragma unroll
    for (int q = 0; q < 4; q++) {
        float x0 = fmaxf(a[q * 2] * di + bb[q * 2], 0.f);
        float x1 = fmaxf(a[q * 2 + 1] * di + bb[q * 2 + 1], 0.f);
        o[q] = __floats2half2_rn(x0, x1);
    }
    *(float4*)(Hout + (size_t)i * D + f) = *(float4*)o;
}

__global__ __launch_bounds__(256) void k_agg_out(const __half* __restrict__ T,
                                                 const int* __restrict__ excl,
                                                 const int* __restrict__ boff,
                                                 const int* __restrict__ col,
                                                 const int* __restrict__ cnt,
                                                 const float* __restrict__ bias,
                                                 float* __restrict__ Of) {
    int i = blockIdx.x * 16 + (threadIdx.x >> 4);
    int lane = threadIdx.x & 63;
    int sl = threadIdx.x & 15;
    int f = sl * 8;
    float di = rsqrtf((float)(cnt[i] + 1));
    float a[8];
    agg_core(T, excl, boff, col, i, f, lane, a);
    float4 bv0 = *(const float4*)(bias + f);
    float4 bv1 = *(const float4*)(bias + f + 4);
    float4 o0 = make_float4(a[0] * di + bv0.x, a[1] * di + bv0.y,
                            a[2] * di + bv0.z, a[3] * di + bv0.w);
    float4 o1 = make_float4(a[4] * di + bv1.x, a[5] * di + bv1.y,
                            a[6] * di + bv1.z, a[7] * di + bv1.w);
    *(float4*)(Of + (size_t)i * D + f) = o0;
    *(float4*)(Of + (size_t)i * D + f + 4) = o1;
}

// ---------------- launch ----------------

extern "C" void kernel_launch(void* const* d_in, const int* in_sizes, int n_in,
                              void* d_out, int out_size, void* d_ws, size_t ws_size,
                              hipStream_t stream) {
    const float* x  = (const float*)d_in[0];
    const int* edge = (const int*)d_in[1];
    const float* W0 = (const float*)d_in[2];
    const float* b0 = (const float*)d_in[3];
    const float* W1 = (const float*)d_in[4];
    const float* b1 = (const float*)d_in[5];
    const float* W2 = (const float*)d_in[6];
    const float* b2 = (const float*)d_in[7];
    const int* src = edge;
    const int* dst = edge + NE;
    float* out = (float*)d_out;

    char* ws = (char*)d_ws;
    size_t off = 0;
    auto alloc = [&](size_t bytes) {
        void* p = ws + off;
        off += (bytes + 255) & ~(size_t)255;
        return p;
    };
    int*   cnt     = (int*)alloc(NN * 4);
    int*   counter = (int*)alloc(256);
    int*   excl    = (int*)alloc(NN * 4);
    int*   bsum    = (int*)alloc(256 * 4);
    int*   boff    = (int*)alloc(256 * 4);
    int*   rank    = (int*)alloc((size_t)NE * 4);
    int*   col     = (int*)alloc((size_t)NE * 4);
    unsigned short* Wh = (unsigned short*)alloc(3 * D * D * 2);
    unsigned short* Wl = (unsigned short*)alloc(3 * D * D * 2);
    __half* Ta = (__half*)alloc((size_t)NPAD * D * 2);
    __half* Tb = (__half*)alloc((size_t)NPAD * D * 2);
    __half* Hb = (__half*)alloc((size_t)NPAD * D * 2);

    hipMemsetAsync(cnt, 0, NN * 4, stream);

    k_degree_convW<<<EGRID + 192, 256, 0, stream>>>(dst, cnt, rank, counter,
                                                    W0, W1, W2, Wh, Wl);
    k_scan_block<<<NB, 256, 0, stream>>>(cnt, excl, bsum, boff, counter);

    const int agrid = NN / 16;          // 3125

    // fused: CSR fill + layer-0 GEMM (Ta = dinv * (x @ W0))
    k_fill_gemm_x<<<GGRID + EGRID, 256, 0, stream>>>(src, dst, excl, boff, rank, col,
                                                     x, Wh, Wl, cnt, Ta);
    // h1 = relu(agg(Ta)+b0)  [fp16]
    k_agg_relu<<<agrid, 256, 0, stream>>>(Ta, excl, boff, col, cnt, b0, Hb);
    // Tb = dinv * (h1 @ W1)
    k_gemm_mfma_h<<<GGRID, 256, 0, stream>>>(Hb, Wh + D * D, Wl + D * D, cnt, Tb);
    // h2 = relu(agg(Tb)+b1)  [fp16]
    k_agg_relu<<<agrid, 256, 0, stream>>>(Tb, excl, boff, col, cnt, b1, Hb);
    // Ta = dinv * (h2 @ W2)
    k_gemm_mfma_h<<<GGRID, 256, 0, stream>>>(Hb, Wh + 2 * D * D, Wl + 2 * D * D, cnt, Ta);
    // out = dinv*agg(Ta) + b2  [fp32]
    k_agg_out<<<agrid, 256, 0, stream>>>(Ta, excl, boff, col, cnt, b2, out);
}